// Round 13
// baseline (102.716 us; speedup 1.0000x reference)
//
#include <hip/hip_runtime.h>
#include <math.h>

#define NN 2048
#define DD 256
#define KK 20
#define HH 4

typedef short short8 __attribute__((ext_vector_type(8)));
typedef float f32x4  __attribute__((ext_vector_type(4)));
typedef _Float16 half8 __attribute__((ext_vector_type(8)));
typedef _Float16 h2    __attribute__((ext_vector_type(2)));

#if defined(__has_builtin)
#  if __has_builtin(__builtin_amdgcn_fdot2)
#    define HAS_FDOT2 1
#  else
#    define HAS_FDOT2 0
#  endif
#else
#  define HAS_FDOT2 0
#endif

struct AllMP  { const unsigned short* xs[6][5]; const int* idx[6]; const unsigned short* xt[6]; int P[6]; };
struct SixPtr { const float* p[6]; };
struct SemB   { const unsigned short* Wmt[6]; const float* bm[6]; };

__device__ inline float wsum(float v){
  #pragma unroll
  for (int o=32;o;o>>=1) v += __shfl_xor(v,o);
  return v;
}
__device__ inline float gsum16(float v){
  #pragma unroll
  for (int o=8;o;o>>=1) v += __shfl_xor(v,o);
  return v;
}
__device__ inline unsigned short f2h(float x){
  return __builtin_bit_cast(unsigned short, (_Float16)x);
}
__device__ inline float h2f(unsigned short u){
  return (float)__builtin_bit_cast(_Float16, u);
}
__device__ inline h2 bch2(unsigned int u){ return __builtin_bit_cast(h2, u); }
__device__ inline h2 packh2(float a, float b){ h2 r; r[0]=(_Float16)a; r[1]=(_Float16)b; return r; }
__device__ inline unsigned int umax2(unsigned int ua, unsigned int ub){
  unsigned int d;
  asm("v_pk_max_f16 %0, %1, %2" : "=v"(d) : "v"(ua), "v"(ub));
  return d;
}
__device__ inline float dot2(h2 a, h2 b, float c){
#if HAS_FDOT2
  return __builtin_amdgcn_fdot2(a, b, c, false);
#else
  return c + (float)a[0]*(float)b[0] + (float)a[1]*(float)b[1];
#endif
}
// async global->LDS, 16B per lane; lds dest = base + 16*lane (wave-uniform base)
__device__ inline void glds16(const void* g, void* l){
  __builtin_amdgcn_global_load_lds(
    (const __attribute__((address_space(1))) unsigned int*)g,
    (__attribute__((address_space(3))) unsigned int*)l, 16, 0, 0);
}

// ---------------- Kernel P: fused prep (wa | xconv | Wt transpose | Wmt transpose) ----------------
__launch_bounds__(256)
__global__ void prep_kernel(SixPtr W, SixPtr a, SixPtr Xp, SixPtr Wm3,
                            float* __restrict__ wa, unsigned short* __restrict__ Xh,
                            unsigned short* __restrict__ Wt, unsigned short* __restrict__ Wmt,
                            float* __restrict__ zero_base, int zero_cnt){
  __shared__ unsigned short T_s[64][68];
  int b = blockIdx.x;
  const int t = threadIdx.x;

  if (b < 24){                       // ---- wa[m,h,d] = sum_e W[m,h,d,e]*a[m,h,e]
    if (b == 0){
      for (int i=t;i<zero_cnt;i+=256) zero_base[i] = 0.f;
    }
    const int m = b >> 2;
    const int local = ((b & 3) << 8) | t;
    const int h = local >> 8, d = local & 255;
    const float4* wrow = (const float4*)(W.p[m] + (size_t)(h*DD + d)*DD);
    const float4* av   = (const float4*)(a.p[m] + h*DD);
    float acc = 0.f;
    #pragma unroll 8
    for (int e=0;e<64;e++){
      float4 wv = wrow[e], xv = av[e];
      acc += wv.x*xv.x + wv.y*xv.y + wv.z*xv.z + wv.w*xv.w;
    }
    wa[m*1024 + local] = acc;
    return;
  }
  b -= 24;
  if (b < 1536){                     // ---- Xh: fp16 copies of feature tables
    int gid = b*256 + t;
    int tb  = gid >> 17;
    int off = gid & 131071;
    float4 v = ((const float4*)Xp.p[tb])[off];
    ushort4 o = { f2h(v.x), f2h(v.y), f2h(v.z), f2h(v.w) };
    ((ushort4*)(Xh + (size_t)tb*NN*DD))[off] = o;
    return;
  }
  b -= 1536;
  const float* src; unsigned short* ob; int R, C, r0, c0;
  if (b < 384){                      // ---- Wt[m][c][q] = f16(W[m][q][c]), swizzled
    int m = b/64, rem = b%64;
    src = W.p[m]; ob = Wt + (size_t)m*256*1024;
    R = 1024; C = 256; r0 = (rem>>2)*64; c0 = (rem&3)*64;
  } else {                           // ---- Wmt[tt][e][d] = f16(Wm[tt][d][e]), swizzled
    int bb = b-384;
    int m = bb/16, rem = bb%16;
    src = Wm3.p[m]; ob = Wmt + (size_t)m*256*256;
    R = 256; C = 256; r0 = (rem>>2)*64; c0 = (rem&3)*64;
  }
  {
    const int rr = t>>4, cc = (t&15)*4;
    #pragma unroll
    for (int i=0;i<4;i++){
      float4 v = *(const float4*)(src + (size_t)(r0+rr+i*16)*C + c0 + cc);
      T_s[cc+0][rr+i*16]=f2h(v.x);
      T_s[cc+1][rr+i*16]=f2h(v.y);
      T_s[cc+2][rr+i*16]=f2h(v.z);
      T_s[cc+3][rr+i*16]=f2h(v.w);
    }
    __syncthreads();
    const int cr = t>>4, rc = (t&15)*4;
    #pragma unroll
    for (int i=0;i<4;i++){
      int c = c0 + cr + i*16;
      ushort4 v = { T_s[cr+i*16][rc+0], T_s[cr+i*16][rc+1],
                    T_s[cr+i*16][rc+2], T_s[cr+i*16][rc+3] };
      int col = (r0 + rc) ^ ((c&7)<<3);
      *(ushort4*)(ob + (size_t)c*R + col) = v;
    }
  }
}

// ------------- Kernel B: gather-max + instance attention -------------
// ONE WAVE handles TWO NODES (n0, n0+1), no barriers, r7 core per node.
// B-node gathers are issued before A's dot phase -> 40 loads in flight per wave;
// same LDS slab reused sequentially (same-wave lockstep => no hazard).
template<int P>
__device__ inline void gatherK(const AllMP& mp, int m, const int* __restrict__ gidx,
                               int l, unsigned int (&v0)[KK], unsigned int (&v1)[KK]){
  #pragma unroll
  for (int k=0;k<KK;k++){
    unsigned int a, bb;
    {
      int id = gidx[k*P];                     // wave-uniform -> s_load
      uint2 r = ((const uint2*)(mp.xs[m][0] + (size_t)id*DD))[l];
      a = r.x; bb = r.y;
    }
    #pragma unroll
    for (int p=1;p<P;p++){
      int id = gidx[k*P+p];
      uint2 u = ((const uint2*)(mp.xs[m][p] + (size_t)id*DD))[l];
      a = umax2(a, u.x); bb = umax2(bb, u.y);
    }
    v0[k] = a; v1[k] = bb;
  }
}

__device__ inline void procNode(int m, int n, int l, int g, int j,
                                const h2 (&wh)[8], float sg,
                                const unsigned int (&v0)[KK], const unsigned int (&v1)[KK],
                                unsigned int (*inst_lds)[128], float (*alpha_lds)[4],
                                unsigned short* __restrict__ ctxh){
  // mirror to LDS for cross-lane dots
  #pragma unroll
  for (int k=0;k<KK;k++)
    *(uint2*)&inst_lds[k][2*l] = make_uint2(v0[k], v1[k]);

  // logits via 16-lane-group dots (same-wave LDS RAW, no barrier)
  float e[KK];
  #pragma unroll
  for (int k=0;k<KK;k++){
    float pr = 0.f;
    #pragma unroll
    for (int c=0;c<4;c++){
      uint2 rr = *(const uint2*)&inst_lds[k][2*(j+16*c)];
      pr = dot2(bch2(rr.x), wh[2*c+0], pr);
      pr = dot2(bch2(rr.y), wh[2*c+1], pr);
    }
    pr = gsum16(pr);
    float logit = pr + sg;
    e[k] = (logit>0.f) ? logit : 0.2f*logit;
  }

  // softmax in registers (replicated within each 16-lane group)
  float mx = e[0];
  #pragma unroll
  for (int k=1;k<KK;k++) mx = fmaxf(mx, e[k]);
  float s = 0.f;
  #pragma unroll
  for (int k=0;k<KK;k++){ e[k] = __expf(e[k]-mx); s += e[k]; }
  float inv = 1.0f/s;
  #pragma unroll
  for (int k=0;k<KK;k++) e[k] *= inv;
  if (j==0){
    #pragma unroll
    for (int k=0;k<KK;k++) alpha_lds[k][g] = e[k];
  }

  // ctx from register copy
  float c[4][4] = {};
  #pragma unroll
  for (int k=0;k<KK;k++){
    float4 af = *(const float4*)&alpha_lds[k][0];
    h2 x0 = bch2(v0[k]), x1 = bch2(v1[k]);
    float f0=(float)x0[0], f1=(float)x0[1], f2=(float)x1[0], f3=(float)x1[1];
    c[0][0]+=af.x*f0; c[0][1]+=af.x*f1; c[0][2]+=af.x*f2; c[0][3]+=af.x*f3;
    c[1][0]+=af.y*f0; c[1][1]+=af.y*f1; c[1][2]+=af.y*f2; c[1][3]+=af.y*f3;
    c[2][0]+=af.z*f0; c[2][1]+=af.z*f1; c[2][2]+=af.z*f2; c[2][3]+=af.z*f3;
    c[3][0]+=af.w*f0; c[3][1]+=af.w*f1; c[3][2]+=af.w*f2; c[3][3]+=af.w*f3;
  }

  unsigned short* cb = ctxh + ((size_t)m*NN + n)*1024;
  const int col = (4*l) ^ ((n&7)<<3);
  #pragma unroll
  for (int h=0;h<4;h++){
    ushort4 o = { f2h(c[h][0]), f2h(c[h][1]), f2h(c[h][2]), f2h(c[h][3]) };
    *(ushort4*)(cb + h*DD + col) = o;
  }
}

template<int P>
__device__ inline void inst_core2(const AllMP& mp, int m, int n0, int l,
                                  const float* __restrict__ wa_all,
                                  unsigned int (*inst_lds)[128], float (*alpha_lds)[4],
                                  unsigned short* __restrict__ ctxh){
  const int g = l >> 4;
  const int j = l & 15;
  const int n1 = n0 + 1;
  const int* __restrict__ gidxA = mp.idx[m] + (size_t)n0*(KK*P);
  const int* __restrict__ gidxB = mp.idx[m] + (size_t)n1*(KK*P);

  h2 wh[8];
  {
    const float4* wab = (const float4*)(wa_all + m*1024 + g*256);
    #pragma unroll
    for (int c=0;c<4;c++){
      float4 wv = wab[j + 16*c];
      wh[2*c]   = packh2(wv.x, wv.y);
      wh[2*c+1] = packh2(wv.z, wv.w);
    }
  }

  float sgA, sgB;
  {
    const uint2* xa = (const uint2*)(mp.xt[m] + (size_t)n0*DD);
    const uint2* xb = (const uint2*)(mp.xt[m] + (size_t)n1*DD);
    float pa = 0.f, pb = 0.f;
    #pragma unroll
    for (int c=0;c<4;c++){
      uint2 ra = xa[j + 16*c], rb = xb[j + 16*c];
      pa = dot2(bch2(ra.x), wh[2*c+0], pa);
      pa = dot2(bch2(ra.y), wh[2*c+1], pa);
      pb = dot2(bch2(rb.x), wh[2*c+0], pb);
      pb = dot2(bch2(rb.y), wh[2*c+1], pb);
    }
    sgA = gsum16(pa);
    sgB = gsum16(pb);
  }

  unsigned int vA0[KK], vA1[KK], vB0[KK], vB1[KK];
  gatherK<P>(mp, m, gidxA, l, vA0, vA1);
  gatherK<P>(mp, m, gidxB, l, vB0, vB1);   // loads in flight during A's dot phase

  procNode(m, n0, l, g, j, wh, sgA, vA0, vA1, inst_lds, alpha_lds, ctxh);
  procNode(m, n1, l, g, j, wh, sgB, vB0, vB1, inst_lds, alpha_lds, ctxh);
}

__launch_bounds__(64)
__global__ void inst_attn_kernel(AllMP mp, const float* __restrict__ wa_all,
                                 unsigned short* __restrict__ ctxh){
  __shared__ unsigned int inst_lds[KK][128];   // 10 KB, reused for both nodes
  __shared__ float alpha_lds[KK][4];           // 320 B
  const int m = blockIdx.y;
  const int n0 = blockIdx.x*2;
  const int l = threadIdx.x;                   // one wave
  switch(mp.P[m]){
    case 3: inst_core2<3>(mp,m,n0,l,wa_all,inst_lds,alpha_lds,ctxh); break;
    case 4: inst_core2<4>(mp,m,n0,l,wa_all,inst_lds,alpha_lds,ctxh); break;
    default: inst_core2<5>(mp,m,n0,l,wa_all,inst_lds,alpha_lds,ctxh); break;
  }
}

// ---------- Kernel C: Hmp[m] = (1/H) * ctx_f16 @ W_f16 (MFMA, dbuf glds, 1 barrier/iter) ----------
__launch_bounds__(256)
__global__ void gemm_kernel(const unsigned short* __restrict__ ctxh,
                            const unsigned short* __restrict__ Wt,
                            unsigned short* __restrict__ Hmp){
  __shared__ unsigned short A_s[2][64][64];
  __shared__ unsigned short B_s[2][64][64];
  const int m  = blockIdx.z;
  const int n0 = blockIdx.x*64, c0 = blockIdx.y*64;
  const int t  = threadIdx.x;
  const int l  = t & 63;
  const int wid  = t >> 6;
  const int wrow = wid & 1, wcol = wid >> 1;
  const unsigned short* Abase = ctxh + (size_t)m*NN*1024;
  const unsigned short* Bbase = Wt   + (size_t)m*256*1024;

  f32x4 acc[2][2] = {};
  const int row8 = l>>3, seg = l&7;

  {
    #pragma unroll
    for (int i=0;i<2;i++){
      const int r = wid*16 + i*8;
      glds16(Abase + (size_t)(n0+r+row8)*1024 + 0 + seg*8, &A_s[0][r][0]);
      glds16(Bbase + (size_t)(c0+r+row8)*1024 + 0 + seg*8, &B_s[0][r][0]);
    }
  }
  __syncthreads();

  #pragma unroll 2
  for (int it=0; it<16; it++){
    const int buf = it&1;
    if (it<15){
      const int k0 = (it+1)*64;
      #pragma unroll
      for (int i=0;i<2;i++){
        const int r = wid*16 + i*8;
        glds16(Abase + (size_t)(n0+r+row8)*1024 + k0 + seg*8, &A_s[buf^1][r][0]);
        glds16(Bbase + (size_t)(c0+r+row8)*1024 + k0 + seg*8, &B_s[buf^1][r][0]);
      }
    }
    __builtin_amdgcn_s_setprio(1);
    #pragma unroll
    for (int kf=0;kf<2;kf++){
      half8 a[2], b[2];
      const int s = kf*4 + (l>>4);
      #pragma unroll
      for (int mr=0;mr<2;mr++){
        const int row = wrow*32 + mr*16 + (l&15);
        a[mr] = __builtin_bit_cast(half8, *(const short8*)&A_s[buf][row][(s ^ (row&7))*8]);
      }
      #pragma unroll
      for (int nr=0;nr<2;nr++){
        const int col = wcol*32 + nr*16 + (l&15);
        b[nr] = __builtin_bit_cast(half8, *(const short8*)&B_s[buf][col][(s ^ (col&7))*8]);
      }
      #pragma unroll
      for (int mr=0;mr<2;mr++)
        #pragma unroll
        for (int nr=0;nr<2;nr++)
          acc[mr][nr] = __builtin_amdgcn_mfma_f32_16x16x32_f16(a[mr], b[nr], acc[mr][nr], 0,0,0);
    }
    __builtin_amdgcn_s_setprio(0);
    __syncthreads();
  }

  unsigned short* out = Hmp + (size_t)m*NN*DD;
  #pragma unroll
  for (int mr=0;mr<2;mr++){
    const int rbase = n0 + wrow*32 + mr*16 + (l>>4)*4;
    #pragma unroll
    for (int nr=0;nr<2;nr++){
      const int col = c0 + wcol*32 + nr*16 + (l&15);
      #pragma unroll
      for (int r=0;r<4;r++){
        const int rw = rbase + r;
        out[(size_t)rw*DD + (col ^ ((rw&7)<<3))] = f2h(acc[mr][nr][r]*0.25f);
      }
    }
  }
}

// ------- Kernel E (MFMA): sem_sum[m,e] += sum_n tanh(Hmp[m,n,:]·Wm[:,e] + bm[e]) -------
__launch_bounds__(256)
__global__ void sem_kernel(const unsigned short* __restrict__ Hmp, SemB sb,
                           float* __restrict__ sem_sum){
  __shared__ unsigned short A_s[64][256];
  __shared__ unsigned short B_s[64][256];
  const int m  = blockIdx.z;
  const int n0 = blockIdx.x*64, c0 = blockIdx.y*64;
  const int t  = threadIdx.x, l = t & 63, wid = t >> 6;
  const int wrow = wid & 1, wcol = wid >> 1;
  const unsigned short* Ab = Hmp + (size_t)m*NN*DD;
  const unsigned short* Bb = sb.Wmt[m];

  const int row2 = l>>5, seg = l&31;
  #pragma unroll
  for (int i=0;i<8;i++){
    const int r = wid*16 + i*2;
    glds16(Ab + (size_t)(n0+r+row2)*DD + seg*8, &A_s[r][0]);
    glds16(Bb + (size_t)(c0+r+row2)*DD + seg*8, &B_s[r][0]);
  }
  __syncthreads();

  f32x4 acc[2][2] = {};
  #pragma unroll
  for (int kf=0; kf<8; kf++){
    const int s = kf*4 + (l>>4);
    half8 a[2], b[2];
    #pragma unroll
    for (int mr=0;mr<2;mr++){
      int row = wrow*32 + mr*16 + (l&15);
      int ss = (s&24) | ((s&7)^(row&7));
      a[mr] = __builtin_bit_cast(half8, *(const short8*)((const char*)&A_s[0][0] + row*512 + ss*16));
    }
    #pragma unroll
    for (int nr=0;nr<2;nr++){
      int row = wcol*32 + nr*16 + (l&15);
      int ss = (s&24) | ((s&7)^(row&7));
      b[nr] = __builtin_bit_cast(half8, *(const short8*)((const char*)&B_s[0][0] + row*512 + ss*16));
    }
    #pragma unroll
    for (int mr=0;mr<2;mr++)
      #pragma unroll
      for (int nr=0;nr<2;nr++)
        acc[mr][nr] = __builtin_amdgcn_mfma_f32_16x16x32_f16(a[mr], b[nr], acc[mr][nr], 0,0,0);
  }

  #pragma unroll
  for (int nr=0;nr<2;nr++){
    const int col = c0 + wcol*32 + nr*16 + (l&15);
    float b = sb.bm[m][col];
    float sv = 0.f;
    #pragma unroll
    for (int mr=0;mr<2;mr++)
      #pragma unroll
      for (int r=0;r<4;r++)
        sv += tanhf(acc[mr][nr][r] + b);
    sv += __shfl_xor(sv,16);
    sv += __shfl_xor(sv,32);
    if (l < 16) atomicAdd(&sem_sum[m*DD + col], sv);
  }
}

// ------- Kernel G (fused beta+combine) -------
__launch_bounds__(256)
__global__ void combine_kernel(const unsigned short* __restrict__ Hmp,
                               const float* __restrict__ sem_sum,
                               const float* __restrict__ qm0, const float* __restrict__ qm1,
                               const float* __restrict__ qm2,
                               float* __restrict__ out){
  const int type = blockIdx.y;
  const int start = (type==0) ? 0 : (type==1) ? 2 : 5;
  const int P = (type==0) ? 2 : (type==1) ? 3 : 1;
  const float* qm = (type==0) ? qm0 : (type==1) ? qm1 : qm2;
  const int t = threadIdx.x;
  __shared__ float red[3][4];
  __shared__ float beta_s[3];

  float q = qm[t];
  #pragma unroll
  for (int p=0;p<3;p++){
    if (p < P){
      float sm = sem_sum[(start+p)*DD + t] * (1.0f/NN);
      float v = wsum(tanhf(sm)*q);
      if ((t&63)==0) red[p][t>>6] = v;
    }
  }
  __syncthreads();
  if (t==0){
    float logits[3], e[3];
    float mx = -INFINITY;
    #pragma unroll
    for (int p=0;p<3;p++){
      if (p < P){
        logits[p] = red[p][0]+red[p][1]+red[p][2]+red[p][3];
        mx = fmaxf(mx, logits[p]);
      }
    }
    float s = 0.f;
    #pragma unroll
    for (int p=0;p<3;p++){
      if (p < P){ e[p] = __expf(logits[p]-mx); s += e[p]; }
    }
    #pragma unroll
    for (int p=0;p<3;p++)
      if (p < P) beta_s[p] = e[p]/s;
  }
  __syncthreads();

  if (blockIdx.x==0 && t<P)
    out[(size_t)3*NN*DD + start + t] = beta_s[t];

  const int n0 = blockIdx.x*4;
  #pragma unroll
  for (int r=0;r<4;r++){
    const int n = n0 + r;
    const int ds = t ^ ((n&7)<<3);
    const unsigned short* base = Hmp + ((size_t)start*NN + n)*DD + ds;
    float acc = 0.f;
    #pragma unroll
    for (int p=0;p<3;p++)
      if (p < P) acc += beta_s[p]*h2f(base[(size_t)p*NN*DD]);
    out[((size_t)type*NN + n)*DD + t] = acc;
  }
}

extern "C" void kernel_launch(void* const* d_in, const int* in_sizes, int n_in,
                              void* d_out, int out_size, void* d_ws, size_t ws_size,
                              hipStream_t stream) {
  SixPtr Xp; Xp.p[0]=(const float*)d_in[0]; Xp.p[1]=(const float*)d_in[1]; Xp.p[2]=(const float*)d_in[2];
  for (int i=3;i<6;i++) Xp.p[i]=Xp.p[0];

  SixPtr Wl, al;
  for (int m=0;m<6;m++){ Wl.p[m] = (const float*)d_in[9+2*m]; al.p[m] = (const float*)d_in[10+2*m]; }
  const float* Wm_[3]; const float* bm_[3]; const float* qm_[3];
  for (int tt=0;tt<3;tt++){
    Wm_[tt] = (const float*)d_in[21+3*tt];
    bm_[tt] = (const float*)d_in[22+3*tt];
    qm_[tt] = (const float*)d_in[23+3*tt];
  }
  SixPtr Wm3; for (int i=0;i<6;i++) Wm3.p[i] = Wm_[i<3?i:0];

  // ---- workspace layout (~46 MB; ws_size = 256 MiB) ----
  char* ws = (char*)d_ws;
  float* wa_all  = (float*)ws;                               ws += 6*1024*4;
  float* sem_sum = (float*)ws;                               ws += 6*DD*4;
  unsigned short* Hmp  = (unsigned short*)ws;                ws += (size_t)6*NN*DD*2;
  unsigned short* Wt   = (unsigned short*)ws;                ws += (size_t)6*256*1024*2;
  unsigned short* Wmt  = (unsigned short*)ws;                ws += (size_t)3*256*256*2;
  unsigned short* Xh   = (unsigned short*)ws;                ws += (size_t)3*NN*DD*2;
  unsigned short* ctxh = (unsigned short*)ws;                // 6*NN*1024*2 = 24 MB

  AllMP mp;
  for (int m=0;m<6;m++) mp.idx[m] = (const int*)d_in[3+m];
  const int P_[6] = {3,5,3,3,4,5};
  for (int m=0;m<6;m++) mp.P[m] = P_[m];
  const int xt_t[6] = {0,0,1,1,1,2};
  const int gp_t[6][5] = {
    {0,1,0,0,0}, {0,1,2,1,0}, {1,2,1,1,1},
    {1,0,1,1,1}, {1,0,0,1,1}, {2,1,0,1,2}};
  for (int m=0;m<6;m++){
    mp.xt[m] = Xh + (size_t)xt_t[m]*NN*DD;
    for (int p=0;p<5;p++) mp.xs[m][p] = Xh + (size_t)gp_t[m][p]*NN*DD;
  }

  SemB sb;
  const int type_of[6] = {0,0,1,1,1,2};
  for (int m=0;m<6;m++){
    sb.Wmt[m] = Wmt + (size_t)type_of[m]*256*256;
    sb.bm[m]  = bm_[type_of[m]];
  }

  prep_kernel<<<dim3(24+1536+384+48),dim3(256),0,stream>>>(
      Wl, al, Xp, Wm3, wa_all, Xh, Wt, Wmt, sem_sum, 6*DD);

  inst_attn_kernel<<<dim3(NN/2,6),dim3(64),0,stream>>>(mp, wa_all, ctxh);
  gemm_kernel<<<dim3(32,4,6),dim3(256),0,stream>>>(ctxh, Wt, Hmp);
  sem_kernel<<<dim3(32,4,6),dim3(256),0,stream>>>(Hmp, sb, sem_sum);

  float* out = (float*)d_out;
  combine_kernel<<<dim3(NN/4,3),dim3(256),0,stream>>>(Hmp, sem_sum, qm_[0], qm_[1], qm_[2], out);
}

// Round 15
// 90.567 us; speedup vs baseline: 1.1341x; 1.1341x over previous
//
#include <hip/hip_runtime.h>
#include <math.h>

#define NN 2048
#define DD 256
#define KK 20
#define HH 4

typedef short short8 __attribute__((ext_vector_type(8)));
typedef float f32x4  __attribute__((ext_vector_type(4)));
typedef _Float16 half8 __attribute__((ext_vector_type(8)));
typedef _Float16 h2    __attribute__((ext_vector_type(2)));

#if defined(__has_builtin)
#  if __has_builtin(__builtin_amdgcn_fdot2)
#    define HAS_FDOT2 1
#  else
#    define HAS_FDOT2 0
#  endif
#else
#  define HAS_FDOT2 0
#endif

struct AllMP  { const unsigned short* xs[6][5]; const int* idx[6]; const unsigned short* xt[6]; int P[6]; };
struct SixPtr { const float* p[6]; };
struct SemB   { const unsigned short* Wmt[6]; const float* bm[6]; };

__device__ inline float wsum(float v){
  #pragma unroll
  for (int o=32;o;o>>=1) v += __shfl_xor(v,o);
  return v;
}
__device__ inline float gsum16(float v){
  #pragma unroll
  for (int o=8;o;o>>=1) v += __shfl_xor(v,o);
  return v;
}
__device__ inline unsigned short f2h(float x){
  return __builtin_bit_cast(unsigned short, (_Float16)x);
}
__device__ inline float h2f(unsigned short u){
  return (float)__builtin_bit_cast(_Float16, u);
}
__device__ inline h2 bch2(unsigned int u){ return __builtin_bit_cast(h2, u); }
__device__ inline h2 packh2(float a, float b){ h2 r; r[0]=(_Float16)a; r[1]=(_Float16)b; return r; }
__device__ inline unsigned int umax2(unsigned int ua, unsigned int ub){
  unsigned int d;
  asm("v_pk_max_f16 %0, %1, %2" : "=v"(d) : "v"(ua), "v"(ub));
  return d;
}
__device__ inline float dot2(h2 a, h2 b, float c){
#if HAS_FDOT2
  return __builtin_amdgcn_fdot2(a, b, c, false);
#else
  return c + (float)a[0]*(float)b[0] + (float)a[1]*(float)b[1];
#endif
}
// async global->LDS, 16B per lane; lds dest = base + 16*lane (wave-uniform base)
__device__ inline void glds16(const void* g, void* l){
  __builtin_amdgcn_global_load_lds(
    (const __attribute__((address_space(1))) unsigned int*)g,
    (__attribute__((address_space(3))) unsigned int*)l, 16, 0, 0);
}

// ---------------- Kernel P: fused prep (wa | xconv | Wt transpose | Wmt transpose) ----------------
// All transposed fp16 weight tables stored PRE-SWIZZLED: element [row][col] at
// col ^ ((row&7)<<3) -> linear LDS staging later.
__launch_bounds__(256)
__global__ void prep_kernel(SixPtr W, SixPtr a, SixPtr Xp, SixPtr Wm3,
                            float* __restrict__ wa, unsigned short* __restrict__ Xh,
                            unsigned short* __restrict__ Wt, unsigned short* __restrict__ Wmt,
                            float* __restrict__ zero_base, int zero_cnt){
  __shared__ unsigned short T_s[64][68];
  int b = blockIdx.x;
  const int t = threadIdx.x;

  if (b < 24){                       // ---- wa[m,h,d] = sum_e W[m,h,d,e]*a[m,h,e]
    if (b == 0){
      for (int i=t;i<zero_cnt;i+=256) zero_base[i] = 0.f;
    }
    const int m = b >> 2;
    const int local = ((b & 3) << 8) | t;
    const int h = local >> 8, d = local & 255;
    const float4* wrow = (const float4*)(W.p[m] + (size_t)(h*DD + d)*DD);
    const float4* av   = (const float4*)(a.p[m] + h*DD);
    float acc = 0.f;
    #pragma unroll 8
    for (int e=0;e<64;e++){
      float4 wv = wrow[e], xv = av[e];
      acc += wv.x*xv.x + wv.y*xv.y + wv.z*xv.z + wv.w*xv.w;
    }
    wa[m*1024 + local] = acc;
    return;
  }
  b -= 24;
  if (b < 1536){                     // ---- Xh: fp16 copies of feature tables
    int gid = b*256 + t;
    int tb  = gid >> 17;
    int off = gid & 131071;
    float4 v = ((const float4*)Xp.p[tb])[off];
    ushort4 o = { f2h(v.x), f2h(v.y), f2h(v.z), f2h(v.w) };
    ((ushort4*)(Xh + (size_t)tb*NN*DD))[off] = o;
    return;
  }
  b -= 1536;
  const float* src; unsigned short* ob; int R, C, r0, c0;
  if (b < 384){                      // ---- Wt[m][c][q] = f16(W[m][q][c]), swizzled
    int m = b/64, rem = b%64;
    src = W.p[m]; ob = Wt + (size_t)m*256*1024;
    R = 1024; C = 256; r0 = (rem>>2)*64; c0 = (rem&3)*64;
  } else {                           // ---- Wmt[tt][e][d] = f16(Wm[tt][d][e]), swizzled
    int bb = b-384;
    int m = bb/16, rem = bb%16;
    src = Wm3.p[m]; ob = Wmt + (size_t)m*256*256;
    R = 256; C = 256; r0 = (rem>>2)*64; c0 = (rem&3)*64;
  }
  {
    const int rr = t>>4, cc = (t&15)*4;
    #pragma unroll
    for (int i=0;i<4;i++){
      float4 v = *(const float4*)(src + (size_t)(r0+rr+i*16)*C + c0 + cc);
      T_s[cc+0][rr+i*16]=f2h(v.x);
      T_s[cc+1][rr+i*16]=f2h(v.y);
      T_s[cc+2][rr+i*16]=f2h(v.z);
      T_s[cc+3][rr+i*16]=f2h(v.w);
    }
    __syncthreads();
    const int cr = t>>4, rc = (t&15)*4;
    #pragma unroll
    for (int i=0;i<4;i++){
      int c = c0 + cr + i*16;
      ushort4 v = { T_s[cr+i*16][rc+0], T_s[cr+i*16][rc+1],
                    T_s[cr+i*16][rc+2], T_s[cr+i*16][rc+3] };
      int col = (r0 + rc) ^ ((c&7)<<3);
      *(ushort4*)(ob + (size_t)c*R + col) = v;
    }
  }
}

// ------------- Kernel B: gather-max + instance attention -------------
// ONE WAVE PER (n,m), no barriers — the proven r7 core. Only change vs r7:
// softmax without max-subtraction (logits O(+-1); r10 proved exact to tolerance
// with fp32 accumulation, which is kept verbatim here).
template<int P>
__device__ inline void inst_core(const AllMP& mp, int m, int n, int l,
                                 const float* __restrict__ wa_all,
                                 unsigned int (*inst_lds)[128], float (*alpha_lds)[4],
                                 unsigned short* __restrict__ ctxh){
  const int g = l >> 4;   // head group
  const int j = l & 15;   // lane in group
  const int* __restrict__ gidx = mp.idx[m] + (size_t)n*(KK*P);

  // wa for head g, this lane's 16 dims {4(j+16c) .. +3}
  h2 wh[8];
  {
    const float4* wab = (const float4*)(wa_all + m*1024 + g*256);
    #pragma unroll
    for (int c=0;c<4;c++){
      float4 wv = wab[j + 16*c];
      wh[2*c]   = packh2(wv.x, wv.y);
      wh[2*c+1] = packh2(wv.z, wv.w);
    }
  }

  // sg = Xt[n]·wa[g] via group reduce
  float sg;
  {
    const uint2* xb = (const uint2*)(mp.xt[m] + (size_t)n*DD);
    float p_ = 0.f;
    #pragma unroll
    for (int c=0;c<4;c++){
      uint2 rr = xb[j + 16*c];
      p_ = dot2(bch2(rr.x), wh[2*c+0], p_);
      p_ = dot2(bch2(rr.y), wh[2*c+1], p_);
    }
    sg = gsum16(p_);
  }

  // Phase 1: gather-max. Lane l owns cols 4l..4l+3; keep in regs AND mirror to LDS.
  unsigned int v0[KK], v1[KK];
  #pragma unroll
  for (int k=0;k<KK;k++){
    unsigned int a, bb;
    {
      int id = gidx[k*P];                     // wave-uniform -> s_load
      uint2 r = ((const uint2*)(mp.xs[m][0] + (size_t)id*DD))[l];
      a = r.x; bb = r.y;
    }
    #pragma unroll
    for (int p=1;p<P;p++){
      int id = gidx[k*P+p];
      uint2 u = ((const uint2*)(mp.xs[m][p] + (size_t)id*DD))[l];
      a = umax2(a, u.x); bb = umax2(bb, u.y);
    }
    v0[k] = a; v1[k] = bb;
    *(uint2*)&inst_lds[k][2*l] = make_uint2(a, bb);
  }

  // Phase 2: logits via 16-lane-group dots (same-wave LDS RAW, no barrier)
  float e[KK];
  #pragma unroll
  for (int k=0;k<KK;k++){
    float pr = 0.f;
    #pragma unroll
    for (int c=0;c<4;c++){
      uint2 rr = *(const uint2*)&inst_lds[k][2*(j+16*c)];
      pr = dot2(bch2(rr.x), wh[2*c+0], pr);
      pr = dot2(bch2(rr.y), wh[2*c+1], pr);
    }
    pr = gsum16(pr);
    float logit = pr + sg;
    // leaky_relu then exp directly (no max-sub; r10-proven safe with fp32 accum)
    e[k] = __expf((logit>0.f) ? logit : 0.2f*logit);
  }

  // Phase 3: denominator + normalized alpha (replicated within 16-lane group)
  float s = 0.f;
  #pragma unroll
  for (int k=0;k<KK;k++) s += e[k];
  const float inv = 1.0f/s;
  if (j==0){
    #pragma unroll
    for (int k=0;k<KK;k++) alpha_lds[k][g] = e[k]*inv;
  }

  // Phase 4: ctx from REGISTER copy of inst; fp32 accumulate (r7 verbatim)
  float c[4][4] = {};
  #pragma unroll
  for (int k=0;k<KK;k++){
    float4 af = *(const float4*)&alpha_lds[k][0];   // broadcast read
    h2 x0 = bch2(v0[k]), x1 = bch2(v1[k]);
    float f0=(float)x0[0], f1=(float)x0[1], f2=(float)x1[0], f3=(float)x1[1];
    c[0][0]+=af.x*f0; c[0][1]+=af.x*f1; c[0][2]+=af.x*f2; c[0][3]+=af.x*f3;
    c[1][0]+=af.y*f0; c[1][1]+=af.y*f1; c[1][2]+=af.y*f2; c[1][3]+=af.y*f3;
    c[2][0]+=af.z*f0; c[2][1]+=af.z*f1; c[2][2]+=af.z*f2; c[2][3]+=af.z*f3;
    c[3][0]+=af.w*f0; c[3][1]+=af.w*f1; c[3][2]+=af.w*f2; c[3][3]+=af.w*f3;
  }

  // store pre-swizzled fp16 ctx
  unsigned short* cb = ctxh + ((size_t)m*NN + n)*1024;
  const int col = (4*l) ^ ((n&7)<<3);
  #pragma unroll
  for (int h=0;h<4;h++){
    ushort4 o = { f2h(c[h][0]), f2h(c[h][1]), f2h(c[h][2]), f2h(c[h][3]) };
    *(ushort4*)(cb + h*DD + col) = o;
  }
}

__launch_bounds__(64)
__global__ void inst_attn_kernel(AllMP mp, const float* __restrict__ wa_all,
                                 unsigned short* __restrict__ ctxh){
  __shared__ unsigned int inst_lds[KK][128];   // 10 KB, packed fp16
  __shared__ float alpha_lds[KK][4];           // 320 B
  const int m = blockIdx.y;
  const int n = blockIdx.x;
  const int l = threadIdx.x;                   // one wave
  switch(mp.P[m]){
    case 3: inst_core<3>(mp,m,n,l,wa_all,inst_lds,alpha_lds,ctxh); break;
    case 4: inst_core<4>(mp,m,n,l,wa_all,inst_lds,alpha_lds,ctxh); break;
    default: inst_core<5>(mp,m,n,l,wa_all,inst_lds,alpha_lds,ctxh); break;
  }
}

// ---------- Kernel C: Hmp[m] = (1/H) * ctx_f16 @ W_f16 (MFMA, dbuf glds, 1 barrier/iter) ----------
__launch_bounds__(256)
__global__ void gemm_kernel(const unsigned short* __restrict__ ctxh,
                            const unsigned short* __restrict__ Wt,
                            unsigned short* __restrict__ Hmp){
  __shared__ unsigned short A_s[2][64][64];
  __shared__ unsigned short B_s[2][64][64];
  const int m  = blockIdx.z;
  const int n0 = blockIdx.x*64, c0 = blockIdx.y*64;
  const int t  = threadIdx.x;
  const int l  = t & 63;
  const int wid  = t >> 6;
  const int wrow = wid & 1, wcol = wid >> 1;
  const unsigned short* Abase = ctxh + (size_t)m*NN*1024;
  const unsigned short* Bbase = Wt   + (size_t)m*256*1024;

  f32x4 acc[2][2] = {};
  const int row8 = l>>3, seg = l&7;

  {
    #pragma unroll
    for (int i=0;i<2;i++){
      const int r = wid*16 + i*8;
      glds16(Abase + (size_t)(n0+r+row8)*1024 + 0 + seg*8, &A_s[0][r][0]);
      glds16(Bbase + (size_t)(c0+r+row8)*1024 + 0 + seg*8, &B_s[0][r][0]);
    }
  }
  __syncthreads();

  #pragma unroll 2
  for (int it=0; it<16; it++){
    const int buf = it&1;
    if (it<15){
      const int k0 = (it+1)*64;
      #pragma unroll
      for (int i=0;i<2;i++){
        const int r = wid*16 + i*8;
        glds16(Abase + (size_t)(n0+r+row8)*1024 + k0 + seg*8, &A_s[buf^1][r][0]);
        glds16(Bbase + (size_t)(c0+r+row8)*1024 + k0 + seg*8, &B_s[buf^1][r][0]);
      }
    }
    __builtin_amdgcn_s_setprio(1);
    #pragma unroll
    for (int kf=0;kf<2;kf++){
      half8 a[2], b[2];
      const int s = kf*4 + (l>>4);
      #pragma unroll
      for (int mr=0;mr<2;mr++){
        const int row = wrow*32 + mr*16 + (l&15);
        a[mr] = __builtin_bit_cast(half8, *(const short8*)&A_s[buf][row][(s ^ (row&7))*8]);
      }
      #pragma unroll
      for (int nr=0;nr<2;nr++){
        const int col = wcol*32 + nr*16 + (l&15);
        b[nr] = __builtin_bit_cast(half8, *(const short8*)&B_s[buf][col][(s ^ (col&7))*8]);
      }
      #pragma unroll
      for (int mr=0;mr<2;mr++)
        #pragma unroll
        for (int nr=0;nr<2;nr++)
          acc[mr][nr] = __builtin_amdgcn_mfma_f32_16x16x32_f16(a[mr], b[nr], acc[mr][nr], 0,0,0);
    }
    __builtin_amdgcn_s_setprio(0);
    __syncthreads();
  }

  unsigned short* out = Hmp + (size_t)m*NN*DD;
  #pragma unroll
  for (int mr=0;mr<2;mr++){
    const int rbase = n0 + wrow*32 + mr*16 + (l>>4)*4;
    #pragma unroll
    for (int nr=0;nr<2;nr++){
      const int col = c0 + wcol*32 + nr*16 + (l&15);
      #pragma unroll
      for (int r=0;r<4;r++){
        const int rw = rbase + r;
        out[(size_t)rw*DD + (col ^ ((rw&7)<<3))] = f2h(acc[mr][nr][r]*0.25f);
      }
    }
  }
}

// ------- Kernel E (MFMA): sem_sum[m,e] += sum_n tanh(Hmp[m,n,:]·Wm[:,e] + bm[e]) -------
__launch_bounds__(256)
__global__ void sem_kernel(const unsigned short* __restrict__ Hmp, SemB sb,
                           float* __restrict__ sem_sum){
  __shared__ unsigned short A_s[64][256];
  __shared__ unsigned short B_s[64][256];
  const int m  = blockIdx.z;
  const int n0 = blockIdx.x*64, c0 = blockIdx.y*64;
  const int t  = threadIdx.x, l = t & 63, wid = t >> 6;
  const int wrow = wid & 1, wcol = wid >> 1;
  const unsigned short* Ab = Hmp + (size_t)m*NN*DD;
  const unsigned short* Bb = sb.Wmt[m];

  const int row2 = l>>5, seg = l&31;
  #pragma unroll
  for (int i=0;i<8;i++){
    const int r = wid*16 + i*2;
    glds16(Ab + (size_t)(n0+r+row2)*DD + seg*8, &A_s[r][0]);
    glds16(Bb + (size_t)(c0+r+row2)*DD + seg*8, &B_s[r][0]);
  }
  __syncthreads();

  f32x4 acc[2][2] = {};
  #pragma unroll
  for (int kf=0; kf<8; kf++){
    const int s = kf*4 + (l>>4);
    half8 a[2], b[2];
    #pragma unroll
    for (int mr=0;mr<2;mr++){
      int row = wrow*32 + mr*16 + (l&15);
      int ss = (s&24) | ((s&7)^(row&7));
      a[mr] = __builtin_bit_cast(half8, *(const short8*)((const char*)&A_s[0][0] + row*512 + ss*16));
    }
    #pragma unroll
    for (int nr=0;nr<2;nr++){
      int row = wcol*32 + nr*16 + (l&15);
      int ss = (s&24) | ((s&7)^(row&7));
      b[nr] = __builtin_bit_cast(half8, *(const short8*)((const char*)&B_s[0][0] + row*512 + ss*16));
    }
    #pragma unroll
    for (int mr=0;mr<2;mr++)
      #pragma unroll
      for (int nr=0;nr<2;nr++)
        acc[mr][nr] = __builtin_amdgcn_mfma_f32_16x16x32_f16(a[mr], b[nr], acc[mr][nr], 0,0,0);
  }

  #pragma unroll
  for (int nr=0;nr<2;nr++){
    const int col = c0 + wcol*32 + nr*16 + (l&15);
    float b = sb.bm[m][col];
    float sv = 0.f;
    #pragma unroll
    for (int mr=0;mr<2;mr++)
      #pragma unroll
      for (int r=0;r<4;r++)
        sv += tanhf(acc[mr][nr][r] + b);
    sv += __shfl_xor(sv,16);
    sv += __shfl_xor(sv,32);
    if (l < 16) atomicAdd(&sem_sum[m*DD + col], sv);
  }
}

// ------- Kernel G (fused beta+combine): per block compute beta, then 4 rows of output -------
__launch_bounds__(256)
__global__ void combine_kernel(const unsigned short* __restrict__ Hmp,
                               const float* __restrict__ sem_sum,
                               const float* __restrict__ qm0, const float* __restrict__ qm1,
                               const float* __restrict__ qm2,
                               float* __restrict__ out){
  const int type = blockIdx.y;
  const int start = (type==0) ? 0 : (type==1) ? 2 : 5;
  const int P = (type==0) ? 2 : (type==1) ? 3 : 1;
  const float* qm = (type==0) ? qm0 : (type==1) ? qm1 : qm2;
  const int t = threadIdx.x;
  __shared__ float red[3][4];
  __shared__ float beta_s[3];

  float q = qm[t];
  #pragma unroll
  for (int p=0;p<3;p++){
    if (p < P){
      float sm = sem_sum[(start+p)*DD + t] * (1.0f/NN);
      float v = wsum(tanhf(sm)*q);
      if ((t&63)==0) red[p][t>>6] = v;
    }
  }
  __syncthreads();
  if (t==0){
    float logits[3], e[3];
    float mx = -INFINITY;
    #pragma unroll
    for (int p=0;p<3;p++){
      if (p < P){
        logits[p] = red[p][0]+red[p][1]+red[p][2]+red[p][3];
        mx = fmaxf(mx, logits[p]);
      }
    }
    float s = 0.f;
    #pragma unroll
    for (int p=0;p<3;p++){
      if (p < P){ e[p] = __expf(logits[p]-mx); s += e[p]; }
    }
    #pragma unroll
    for (int p=0;p<3;p++)
      if (p < P) beta_s[p] = e[p]/s;
  }
  __syncthreads();

  if (blockIdx.x==0 && t<P)
    out[(size_t)3*NN*DD + start + t] = beta_s[t];

  const int n0 = blockIdx.x*4;
  #pragma unroll
  for (int r=0;r<4;r++){
    const int n = n0 + r;
    const int ds = t ^ ((n&7)<<3);
    const unsigned short* base = Hmp + ((size_t)start*NN + n)*DD + ds;
    float acc = 0.f;
    #pragma unroll
    for (int p=0;p<3;p++)
      if (p < P) acc += beta_s[p]*h2f(base[(size_t)p*NN*DD]);
    out[((size_t)type*NN + n)*DD + t] = acc;
  }
}

extern "C" void kernel_launch(void* const* d_in, const int* in_sizes, int n_in,
                              void* d_out, int out_size, void* d_ws, size_t ws_size,
                              hipStream_t stream) {
  SixPtr Xp; Xp.p[0]=(const float*)d_in[0]; Xp.p[1]=(const float*)d_in[1]; Xp.p[2]=(const float*)d_in[2];
  for (int i=3;i<6;i++) Xp.p[i]=Xp.p[0];

  SixPtr Wl, al;
  for (int m=0;m<6;m++){ Wl.p[m] = (const float*)d_in[9+2*m]; al.p[m] = (const float*)d_in[10+2*m]; }
  const float* Wm_[3]; const float* bm_[3]; const float* qm_[3];
  for (int tt=0;tt<3;tt++){
    Wm_[tt] = (const float*)d_in[21+3*tt];
    bm_[tt] = (const float*)d_in[22+3*tt];
    qm_[tt] = (const float*)d_in[23+3*tt];
  }
  SixPtr Wm3; for (int i=0;i<6;i++) Wm3.p[i] = Wm_[i<3?i:0];

  // ---- workspace layout (~46 MB; ws_size = 256 MiB) ----
  char* ws = (char*)d_ws;
  float* wa_all  = (float*)ws;                               ws += 6*1024*4;
  float* sem_sum = (float*)ws;                               ws += 6*DD*4;
  unsigned short* Hmp  = (unsigned short*)ws;                ws += (size_t)6*NN*DD*2;
  unsigned short* Wt   = (unsigned short*)ws;                ws += (size_t)6*256*1024*2;
  unsigned short* Wmt  = (unsigned short*)ws;                ws += (size_t)3*256*256*2;
  unsigned short* Xh   = (unsigned short*)ws;                ws += (size_t)3*NN*DD*2;
  unsigned short* ctxh = (unsigned short*)ws;                // 6*NN*1024*2 = 24 MB

  AllMP mp;
  for (int m=0;m<6;m++) mp.idx[m] = (const int*)d_in[3+m];
  const int P_[6] = {3,5,3,3,4,5};
  for (int m=0;m<6;m++) mp.P[m] = P_[m];
  const int xt_t[6] = {0,0,1,1,1,2};
  const int gp_t[6][5] = {
    {0,1,0,0,0}, {0,1,2,1,0}, {1,2,1,1,1},
    {1,0,1,1,1}, {1,0,0,1,1}, {2,1,0,1,2}};
  for (int m=0;m<6;m++){
    mp.xt[m] = Xh + (size_t)xt_t[m]*NN*DD;
    for (int p=0;p<5;p++) mp.xs[m][p] = Xh + (size_t)gp_t[m][p]*NN*DD;
  }

  SemB sb;
  const int type_of[6] = {0,0,1,1,1,2};
  for (int m=0;m<6;m++){
    sb.Wmt[m] = Wmt + (size_t)type_of[m]*256*256;
    sb.bm[m]  = bm_[type_of[m]];
  }

  prep_kernel<<<dim3(24+1536+384+48),dim3(256),0,stream>>>(
      Wl, al, Xp, Wm3, wa_all, Xh, Wt, Wmt, sem_sum, 6*DD);

  inst_attn_kernel<<<dim3(NN,6),dim3(64),0,stream>>>(mp, wa_all, ctxh);
  gemm_kernel<<<dim3(32,4,6),dim3(256),0,stream>>>(ctxh, Wt, Hmp);
  sem_kernel<<<dim3(32,4,6),dim3(256),0,stream>>>(Hmp, sb, sem_sum);

  float* out = (float*)d_out;
  combine_kernel<<<dim3(NN/4,3),dim3(256),0,stream>>>(Hmp, sem_sum, qm_[0], qm_[1], qm_[2], out);
}

// Round 16
// 89.208 us; speedup vs baseline: 1.1514x; 1.0152x over previous
//
#include <hip/hip_runtime.h>
#include <math.h>

#define NN 2048
#define DD 256
#define KK 20
#define HH 4

typedef short short8 __attribute__((ext_vector_type(8)));
typedef float f32x4  __attribute__((ext_vector_type(4)));
typedef _Float16 half8 __attribute__((ext_vector_type(8)));
typedef _Float16 h2    __attribute__((ext_vector_type(2)));

#if defined(__has_builtin)
#  if __has_builtin(__builtin_amdgcn_fdot2)
#    define HAS_FDOT2 1
#  else
#    define HAS_FDOT2 0
#  endif
#else
#  define HAS_FDOT2 0
#endif

struct AllMP  { const unsigned short* xs[6][5]; const int* idx[6]; const unsigned short* xt[6]; int P[6]; };
struct SixPtr { const float* p[6]; };
struct SemB   { const unsigned short* Wmt[6]; const float* bm[6]; };

__device__ inline float wsum(float v){
  #pragma unroll
  for (int o=32;o;o>>=1) v += __shfl_xor(v,o);
  return v;
}
// 16-lane-group sum entirely on the VALU pipe (DPP), zero DS-pipe traffic:
// quad_perm(xor1) -> quad_perm(xor2) -> row_half_mirror -> row_mirror.
#define DPPADD(v, ctrl) \
  ((v) + __builtin_bit_cast(float, __builtin_amdgcn_update_dpp( \
      0, __builtin_bit_cast(int, (v)), (ctrl), 0xF, 0xF, true)))
__device__ inline float gsum16(float v){
  v = DPPADD(v, 0xB1);    // quad_perm [1,0,3,2]  (xor 1)
  v = DPPADD(v, 0x4E);    // quad_perm [2,3,0,1]  (xor 2)
  v = DPPADD(v, 0x141);   // row_half_mirror      (xor within 8)
  v = DPPADD(v, 0x140);   // row_mirror           (xor within 16)
  return v;
}
__device__ inline unsigned short f2h(float x){
  return __builtin_bit_cast(unsigned short, (_Float16)x);
}
__device__ inline float h2f(unsigned short u){
  return (float)__builtin_bit_cast(_Float16, u);
}
__device__ inline h2 bch2(unsigned int u){ return __builtin_bit_cast(h2, u); }
__device__ inline h2 packh2(float a, float b){ h2 r; r[0]=(_Float16)a; r[1]=(_Float16)b; return r; }
__device__ inline unsigned int umax2(unsigned int ua, unsigned int ub){
  unsigned int d;
  asm("v_pk_max_f16 %0, %1, %2" : "=v"(d) : "v"(ua), "v"(ub));
  return d;
}
__device__ inline float dot2(h2 a, h2 b, float c){
#if HAS_FDOT2
  return __builtin_amdgcn_fdot2(a, b, c, false);
#else
  return c + (float)a[0]*(float)b[0] + (float)a[1]*(float)b[1];
#endif
}
// async global->LDS, 16B per lane; lds dest = base + 16*lane (wave-uniform base)
__device__ inline void glds16(const void* g, void* l){
  __builtin_amdgcn_global_load_lds(
    (const __attribute__((address_space(1))) unsigned int*)g,
    (__attribute__((address_space(3))) unsigned int*)l, 16, 0, 0);
}

// ---------------- Kernel P: fused prep (wa | xconv | Wt transpose | Wmt transpose) ----------------
// All transposed fp16 weight tables stored PRE-SWIZZLED: element [row][col] at
// col ^ ((row&7)<<3) -> linear LDS staging later.
__launch_bounds__(256)
__global__ void prep_kernel(SixPtr W, SixPtr a, SixPtr Xp, SixPtr Wm3,
                            float* __restrict__ wa, unsigned short* __restrict__ Xh,
                            unsigned short* __restrict__ Wt, unsigned short* __restrict__ Wmt,
                            float* __restrict__ zero_base, int zero_cnt){
  __shared__ unsigned short T_s[64][68];
  int b = blockIdx.x;
  const int t = threadIdx.x;

  if (b < 24){                       // ---- wa[m,h,d] = sum_e W[m,h,d,e]*a[m,h,e]
    if (b == 0){
      for (int i=t;i<zero_cnt;i+=256) zero_base[i] = 0.f;
    }
    const int m = b >> 2;
    const int local = ((b & 3) << 8) | t;
    const int h = local >> 8, d = local & 255;
    const float4* wrow = (const float4*)(W.p[m] + (size_t)(h*DD + d)*DD);
    const float4* av   = (const float4*)(a.p[m] + h*DD);
    float acc = 0.f;
    #pragma unroll 8
    for (int e=0;e<64;e++){
      float4 wv = wrow[e], xv = av[e];
      acc += wv.x*xv.x + wv.y*xv.y + wv.z*xv.z + wv.w*xv.w;
    }
    wa[m*1024 + local] = acc;
    return;
  }
  b -= 24;
  if (b < 1536){                     // ---- Xh: fp16 copies of feature tables
    int gid = b*256 + t;
    int tb  = gid >> 17;
    int off = gid & 131071;
    float4 v = ((const float4*)Xp.p[tb])[off];
    ushort4 o = { f2h(v.x), f2h(v.y), f2h(v.z), f2h(v.w) };
    ((ushort4*)(Xh + (size_t)tb*NN*DD))[off] = o;
    return;
  }
  b -= 1536;
  const float* src; unsigned short* ob; int R, C, r0, c0;
  if (b < 384){                      // ---- Wt[m][c][q] = f16(W[m][q][c]), swizzled
    int m = b/64, rem = b%64;
    src = W.p[m]; ob = Wt + (size_t)m*256*1024;
    R = 1024; C = 256; r0 = (rem>>2)*64; c0 = (rem&3)*64;
  } else {                           // ---- Wmt[tt][e][d] = f16(Wm[tt][d][e]), swizzled
    int bb = b-384;
    int m = bb/16, rem = bb%16;
    src = Wm3.p[m]; ob = Wmt + (size_t)m*256*256;
    R = 256; C = 256; r0 = (rem>>2)*64; c0 = (rem&3)*64;
  }
  {
    const int rr = t>>4, cc = (t&15)*4;
    #pragma unroll
    for (int i=0;i<4;i++){
      float4 v = *(const float4*)(src + (size_t)(r0+rr+i*16)*C + c0 + cc);
      T_s[cc+0][rr+i*16]=f2h(v.x);
      T_s[cc+1][rr+i*16]=f2h(v.y);
      T_s[cc+2][rr+i*16]=f2h(v.z);
      T_s[cc+3][rr+i*16]=f2h(v.w);
    }
    __syncthreads();
    const int cr = t>>4, rc = (t&15)*4;
    #pragma unroll
    for (int i=0;i<4;i++){
      int c = c0 + cr + i*16;
      ushort4 v = { T_s[cr+i*16][rc+0], T_s[cr+i*16][rc+1],
                    T_s[cr+i*16][rc+2], T_s[cr+i*16][rc+3] };
      int col = (r0 + rc) ^ ((c&7)<<3);
      *(ushort4*)(ob + (size_t)c*R + col) = v;
    }
  }
}

// ------------- Kernel B: gather-max + instance attention -------------
// ONE WAVE PER (n,m), no barriers — r15 core with the 16-lane reductions moved
// from the DS pipe (ds_swizzle) to the VALU pipe (DPP). 84 DS ops/wave deleted.
template<int P>
__device__ inline void inst_core(const AllMP& mp, int m, int n, int l,
                                 const float* __restrict__ wa_all,
                                 unsigned int (*inst_lds)[128], float (*alpha_lds)[4],
                                 unsigned short* __restrict__ ctxh){
  const int g = l >> 4;   // head group
  const int j = l & 15;   // lane in group
  const int* __restrict__ gidx = mp.idx[m] + (size_t)n*(KK*P);

  // wa for head g, this lane's 16 dims {4(j+16c) .. +3}
  h2 wh[8];
  {
    const float4* wab = (const float4*)(wa_all + m*1024 + g*256);
    #pragma unroll
    for (int c=0;c<4;c++){
      float4 wv = wab[j + 16*c];
      wh[2*c]   = packh2(wv.x, wv.y);
      wh[2*c+1] = packh2(wv.z, wv.w);
    }
  }

  // sg = Xt[n]·wa[g] via DPP group reduce
  float sg;
  {
    const uint2* xb = (const uint2*)(mp.xt[m] + (size_t)n*DD);
    float p_ = 0.f;
    #pragma unroll
    for (int c=0;c<4;c++){
      uint2 rr = xb[j + 16*c];
      p_ = dot2(bch2(rr.x), wh[2*c+0], p_);
      p_ = dot2(bch2(rr.y), wh[2*c+1], p_);
    }
    sg = gsum16(p_);
  }

  // Phase 1: gather-max. Lane l owns cols 4l..4l+3; keep in regs AND mirror to LDS.
  unsigned int v0[KK], v1[KK];
  #pragma unroll
  for (int k=0;k<KK;k++){
    unsigned int a, bb;
    {
      int id = gidx[k*P];                     // wave-uniform -> s_load
      uint2 r = ((const uint2*)(mp.xs[m][0] + (size_t)id*DD))[l];
      a = r.x; bb = r.y;
    }
    #pragma unroll
    for (int p=1;p<P;p++){
      int id = gidx[k*P+p];
      uint2 u = ((const uint2*)(mp.xs[m][p] + (size_t)id*DD))[l];
      a = umax2(a, u.x); bb = umax2(bb, u.y);
    }
    v0[k] = a; v1[k] = bb;
    *(uint2*)&inst_lds[k][2*l] = make_uint2(a, bb);
  }

  // Phase 2: logits via 16-lane-group dots (same-wave LDS RAW, no barrier)
  float e[KK];
  #pragma unroll
  for (int k=0;k<KK;k++){
    float pr = 0.f;
    #pragma unroll
    for (int c=0;c<4;c++){
      uint2 rr = *(const uint2*)&inst_lds[k][2*(j+16*c)];
      pr = dot2(bch2(rr.x), wh[2*c+0], pr);
      pr = dot2(bch2(rr.y), wh[2*c+1], pr);
    }
    pr = gsum16(pr);      // DPP, VALU pipe
    float logit = pr + sg;
    // leaky_relu then exp directly (no max-sub; r10/r15-proven safe, fp32 accum)
    e[k] = __expf((logit>0.f) ? logit : 0.2f*logit);
  }

  // Phase 3: denominator + normalized alpha (replicated within 16-lane group)
  float s = 0.f;
  #pragma unroll
  for (int k=0;k<KK;k++) s += e[k];
  const float inv = 1.0f/s;
  if (j==0){
    #pragma unroll
    for (int k=0;k<KK;k++) alpha_lds[k][g] = e[k]*inv;
  }

  // Phase 4: ctx from REGISTER copy of inst; fp32 accumulate
  float c[4][4] = {};
  #pragma unroll
  for (int k=0;k<KK;k++){
    float4 af = *(const float4*)&alpha_lds[k][0];   // broadcast read
    h2 x0 = bch2(v0[k]), x1 = bch2(v1[k]);
    float f0=(float)x0[0], f1=(float)x0[1], f2=(float)x1[0], f3=(float)x1[1];
    c[0][0]+=af.x*f0; c[0][1]+=af.x*f1; c[0][2]+=af.x*f2; c[0][3]+=af.x*f3;
    c[1][0]+=af.y*f0; c[1][1]+=af.y*f1; c[1][2]+=af.y*f2; c[1][3]+=af.y*f3;
    c[2][0]+=af.z*f0; c[2][1]+=af.z*f1; c[2][2]+=af.z*f2; c[2][3]+=af.z*f3;
    c[3][0]+=af.w*f0; c[3][1]+=af.w*f1; c[3][2]+=af.w*f2; c[3][3]+=af.w*f3;
  }

  // store pre-swizzled fp16 ctx
  unsigned short* cb = ctxh + ((size_t)m*NN + n)*1024;
  const int col = (4*l) ^ ((n&7)<<3);
  #pragma unroll
  for (int h=0;h<4;h++){
    ushort4 o = { f2h(c[h][0]), f2h(c[h][1]), f2h(c[h][2]), f2h(c[h][3]) };
    *(ushort4*)(cb + h*DD + col) = o;
  }
}

__launch_bounds__(64)
__global__ void inst_attn_kernel(AllMP mp, const float* __restrict__ wa_all,
                                 unsigned short* __restrict__ ctxh){
  __shared__ unsigned int inst_lds[KK][128];   // 10 KB, packed fp16
  __shared__ float alpha_lds[KK][4];           // 320 B
  const int m = blockIdx.y;
  const int n = blockIdx.x;
  const int l = threadIdx.x;                   // one wave
  switch(mp.P[m]){
    case 3: inst_core<3>(mp,m,n,l,wa_all,inst_lds,alpha_lds,ctxh); break;
    case 4: inst_core<4>(mp,m,n,l,wa_all,inst_lds,alpha_lds,ctxh); break;
    default: inst_core<5>(mp,m,n,l,wa_all,inst_lds,alpha_lds,ctxh); break;
  }
}

// ---------- Kernel C: Hmp[m] = (1/H) * ctx_f16 @ W_f16 (MFMA, dbuf glds, 1 barrier/iter) ----------
__launch_bounds__(256)
__global__ void gemm_kernel(const unsigned short* __restrict__ ctxh,
                            const unsigned short* __restrict__ Wt,
                            unsigned short* __restrict__ Hmp){
  __shared__ unsigned short A_s[2][64][64];
  __shared__ unsigned short B_s[2][64][64];
  const int m  = blockIdx.z;
  const int n0 = blockIdx.x*64, c0 = blockIdx.y*64;
  const int t  = threadIdx.x;
  const int l  = t & 63;
  const int wid  = t >> 6;
  const int wrow = wid & 1, wcol = wid >> 1;
  const unsigned short* Abase = ctxh + (size_t)m*NN*1024;
  const unsigned short* Bbase = Wt   + (size_t)m*256*1024;

  f32x4 acc[2][2] = {};
  const int row8 = l>>3, seg = l&7;

  {
    #pragma unroll
    for (int i=0;i<2;i++){
      const int r = wid*16 + i*8;
      glds16(Abase + (size_t)(n0+r+row8)*1024 + 0 + seg*8, &A_s[0][r][0]);
      glds16(Bbase + (size_t)(c0+r+row8)*1024 + 0 + seg*8, &B_s[0][r][0]);
    }
  }
  __syncthreads();

  #pragma unroll 2
  for (int it=0; it<16; it++){
    const int buf = it&1;
    if (it<15){
      const int k0 = (it+1)*64;
      #pragma unroll
      for (int i=0;i<2;i++){
        const int r = wid*16 + i*8;
        glds16(Abase + (size_t)(n0+r+row8)*1024 + k0 + seg*8, &A_s[buf^1][r][0]);
        glds16(Bbase + (size_t)(c0+r+row8)*1024 + k0 + seg*8, &B_s[buf^1][r][0]);
      }
    }
    __builtin_amdgcn_s_setprio(1);
    #pragma unroll
    for (int kf=0;kf<2;kf++){
      half8 a[2], b[2];
      const int s = kf*4 + (l>>4);
      #pragma unroll
      for (int mr=0;mr<2;mr++){
        const int row = wrow*32 + mr*16 + (l&15);
        a[mr] = __builtin_bit_cast(half8, *(const short8*)&A_s[buf][row][(s ^ (row&7))*8]);
      }
      #pragma unroll
      for (int nr=0;nr<2;nr++){
        const int col = wcol*32 + nr*16 + (l&15);
        b[nr] = __builtin_bit_cast(half8, *(const short8*)&B_s[buf][col][(s ^ (col&7))*8]);
      }
      #pragma unroll
      for (int mr=0;mr<2;mr++)
        #pragma unroll
        for (int nr=0;nr<2;nr++)
          acc[mr][nr] = __builtin_amdgcn_mfma_f32_16x16x32_f16(a[mr], b[nr], acc[mr][nr], 0,0,0);
    }
    __builtin_amdgcn_s_setprio(0);
    __syncthreads();
  }

  unsigned short* out = Hmp + (size_t)m*NN*DD;
  #pragma unroll
  for (int mr=0;mr<2;mr++){
    const int rbase = n0 + wrow*32 + mr*16 + (l>>4)*4;
    #pragma unroll
    for (int nr=0;nr<2;nr++){
      const int col = c0 + wcol*32 + nr*16 + (l&15);
      #pragma unroll
      for (int r=0;r<4;r++){
        const int rw = rbase + r;
        out[(size_t)rw*DD + (col ^ ((rw&7)<<3))] = f2h(acc[mr][nr][r]*0.25f);
      }
    }
  }
}

// ------- Kernel E (MFMA): sem_sum[m,e] += sum_n tanh(Hmp[m,n,:]·Wm[:,e] + bm[e]) -------
__launch_bounds__(256)
__global__ void sem_kernel(const unsigned short* __restrict__ Hmp, SemB sb,
                           float* __restrict__ sem_sum){
  __shared__ unsigned short A_s[64][256];
  __shared__ unsigned short B_s[64][256];
  const int m  = blockIdx.z;
  const int n0 = blockIdx.x*64, c0 = blockIdx.y*64;
  const int t  = threadIdx.x, l = t & 63, wid = t >> 6;
  const int wrow = wid & 1, wcol = wid >> 1;
  const unsigned short* Ab = Hmp + (size_t)m*NN*DD;
  const unsigned short* Bb = sb.Wmt[m];

  const int row2 = l>>5, seg = l&31;
  #pragma unroll
  for (int i=0;i<8;i++){
    const int r = wid*16 + i*2;
    glds16(Ab + (size_t)(n0+r+row2)*DD + seg*8, &A_s[r][0]);
    glds16(Bb + (size_t)(c0+r+row2)*DD + seg*8, &B_s[r][0]);
  }
  __syncthreads();

  f32x4 acc[2][2] = {};
  #pragma unroll
  for (int kf=0; kf<8; kf++){
    const int s = kf*4 + (l>>4);
    half8 a[2], b[2];
    #pragma unroll
    for (int mr=0;mr<2;mr++){
      int row = wrow*32 + mr*16 + (l&15);
      int ss = (s&24) | ((s&7)^(row&7));
      a[mr] = __builtin_bit_cast(half8, *(const short8*)((const char*)&A_s[0][0] + row*512 + ss*16));
    }
    #pragma unroll
    for (int nr=0;nr<2;nr++){
      int row = wcol*32 + nr*16 + (l&15);
      int ss = (s&24) | ((s&7)^(row&7));
      b[nr] = __builtin_bit_cast(half8, *(const short8*)((const char*)&B_s[0][0] + row*512 + ss*16));
    }
    #pragma unroll
    for (int mr=0;mr<2;mr++)
      #pragma unroll
      for (int nr=0;nr<2;nr++)
        acc[mr][nr] = __builtin_amdgcn_mfma_f32_16x16x32_f16(a[mr], b[nr], acc[mr][nr], 0,0,0);
  }

  #pragma unroll
  for (int nr=0;nr<2;nr++){
    const int col = c0 + wcol*32 + nr*16 + (l&15);
    float b = sb.bm[m][col];
    float sv = 0.f;
    #pragma unroll
    for (int mr=0;mr<2;mr++)
      #pragma unroll
      for (int r=0;r<4;r++)
        sv += tanhf(acc[mr][nr][r] + b);
    sv += __shfl_xor(sv,16);
    sv += __shfl_xor(sv,32);
    if (l < 16) atomicAdd(&sem_sum[m*DD + col], sv);
  }
}

// ------- Kernel G (fused beta+combine): per block compute beta, then 4 rows of output -------
__launch_bounds__(256)
__global__ void combine_kernel(const unsigned short* __restrict__ Hmp,
                               const float* __restrict__ sem_sum,
                               const float* __restrict__ qm0, const float* __restrict__ qm1,
                               const float* __restrict__ qm2,
                               float* __restrict__ out){
  const int type = blockIdx.y;
  const int start = (type==0) ? 0 : (type==1) ? 2 : 5;
  const int P = (type==0) ? 2 : (type==1) ? 3 : 1;
  const float* qm = (type==0) ? qm0 : (type==1) ? qm1 : qm2;
  const int t = threadIdx.x;
  __shared__ float red[3][4];
  __shared__ float beta_s[3];

  float q = qm[t];
  #pragma unroll
  for (int p=0;p<3;p++){
    if (p < P){
      float sm = sem_sum[(start+p)*DD + t] * (1.0f/NN);
      float v = wsum(tanhf(sm)*q);
      if ((t&63)==0) red[p][t>>6] = v;
    }
  }
  __syncthreads();
  if (t==0){
    float logits[3], e[3];
    float mx = -INFINITY;
    #pragma unroll
    for (int p=0;p<3;p++){
      if (p < P){
        logits[p] = red[p][0]+red[p][1]+red[p][2]+red[p][3];
        mx = fmaxf(mx, logits[p]);
      }
    }
    float s = 0.f;
    #pragma unroll
    for (int p=0;p<3;p++){
      if (p < P){ e[p] = __expf(logits[p]-mx); s += e[p]; }
    }
    #pragma unroll
    for (int p=0;p<3;p++)
      if (p < P) beta_s[p] = e[p]/s;
  }
  __syncthreads();

  if (blockIdx.x==0 && t<P)
    out[(size_t)3*NN*DD + start + t] = beta_s[t];

  const int n0 = blockIdx.x*4;
  #pragma unroll
  for (int r=0;r<4;r++){
    const int n = n0 + r;
    const int ds = t ^ ((n&7)<<3);
    const unsigned short* base = Hmp + ((size_t)start*NN + n)*DD + ds;
    float acc = 0.f;
    #pragma unroll
    for (int p=0;p<3;p++)
      if (p < P) acc += beta_s[p]*h2f(base[(size_t)p*NN*DD]);
    out[((size_t)type*NN + n)*DD + t] = acc;
  }
}

extern "C" void kernel_launch(void* const* d_in, const int* in_sizes, int n_in,
                              void* d_out, int out_size, void* d_ws, size_t ws_size,
                              hipStream_t stream) {
  SixPtr Xp; Xp.p[0]=(const float*)d_in[0]; Xp.p[1]=(const float*)d_in[1]; Xp.p[2]=(const float*)d_in[2];
  for (int i=3;i<6;i++) Xp.p[i]=Xp.p[0];

  SixPtr Wl, al;
  for (int m=0;m<6;m++){ Wl.p[m] = (const float*)d_in[9+2*m]; al.p[m] = (const float*)d_in[10+2*m]; }
  const float* Wm_[3]; const float* bm_[3]; const float* qm_[3];
  for (int tt=0;tt<3;tt++){
    Wm_[tt] = (const float*)d_in[21+3*tt];
    bm_[tt] = (const float*)d_in[22+3*tt];
    qm_[tt] = (const float*)d_in[23+3*tt];
  }
  SixPtr Wm3; for (int i=0;i<6;i++) Wm3.p[i] = Wm_[i<3?i:0];

  // ---- workspace layout (~46 MB; ws_size = 256 MiB) ----
  char* ws = (char*)d_ws;
  float* wa_all  = (float*)ws;                               ws += 6*1024*4;
  float* sem_sum = (float*)ws;                               ws += 6*DD*4;
  unsigned short* Hmp  = (unsigned short*)ws;                ws += (size_t)6*NN*DD*2;
  unsigned short* Wt   = (unsigned short*)ws;                ws += (size_t)6*256*1024*2;
  unsigned short* Wmt  = (unsigned short*)ws;                ws += (size_t)3*256*256*2;
  unsigned short* Xh   = (unsigned short*)ws;                ws += (size_t)3*NN*DD*2;
  unsigned short* ctxh = (unsigned short*)ws;                // 6*NN*1024*2 = 24 MB

  AllMP mp;
  for (int m=0;m<6;m++) mp.idx[m] = (const int*)d_in[3+m];
  const int P_[6] = {3,5,3,3,4,5};
  for (int m=0;m<6;m++) mp.P[m] = P_[m];
  const int xt_t[6] = {0,0,1,1,1,2};
  const int gp_t[6][5] = {
    {0,1,0,0,0}, {0,1,2,1,0}, {1,2,1,1,1},
    {1,0,1,1,1}, {1,0,0,1,1}, {2,1,0,1,2}};
  for (int m=0;m<6;m++){
    mp.xt[m] = Xh + (size_t)xt_t[m]*NN*DD;
    for (int p=0;p<5;p++) mp.xs[m][p] = Xh + (size_t)gp_t[m][p]*NN*DD;
  }

  SemB sb;
  const int type_of[6] = {0,0,1,1,1,2};
  for (int m=0;m<6;m++){
    sb.Wmt[m] = Wmt + (size_t)type_of[m]*256*256;
    sb.bm[m]  = bm_[type_of[m]];
  }

  prep_kernel<<<dim3(24+1536+384+48),dim3(256),0,stream>>>(
      Wl, al, Xp, Wm3, wa_all, Xh, Wt, Wmt, sem_sum, 6*DD);

  inst_attn_kernel<<<dim3(NN,6),dim3(64),0,stream>>>(mp, wa_all, ctxh);
  gemm_kernel<<<dim3(32,4,6),dim3(256),0,stream>>>(ctxh, Wt, Hmp);
  sem_kernel<<<dim3(32,4,6),dim3(256),0,stream>>>(Hmp, sb, sem_sum);

  float* out = (float*)d_out;
  combine_kernel<<<dim3(NN/4,3),dim3(256),0,stream>>>(Hmp, sem_sum, qm_[0], qm_[1], qm_[2], out);
}